// Round 1
// baseline (49.960 us; speedup 1.0000x reference)
//
#include <hip/hip_runtime.h>

// BatchAllTripletLoss: B=512 embeddings of dim E=128, labels in [0,64).
// out = sum(hinge) / (count(hinge > EPS) + EPS)
// hinge over valid triplets (a,p,n): max(d(a,p) - d(a,n) + MARGIN, 0),
// valid iff a!=p, label[a]==label[p], label[a]!=label[n].

#define BSZ 512
#define EDIM 128

__device__ __forceinline__ float sq(float x) { return x * x; }

__global__ __launch_bounds__(256) void triplet_rows(
    const float* __restrict__ embs,
    const int* __restrict__ labels,
    float* __restrict__ sums,
    float* __restrict__ cnts)
{
    __shared__ float ea[EDIM];      // anchor embedding
    __shared__ float d[BSZ];        // dist row for this anchor
    __shared__ int   lab[BSZ];      // labels
    __shared__ int   plist[BSZ];    // positive indices
    __shared__ int   pcnt;
    __shared__ float wsum[4], wcnt[4];

    const int a   = blockIdx.x;
    const int tid = threadIdx.x;

    // Load anchor row (128 floats = 32 float4)
    if (tid < EDIM / 4) {
        float4 v = reinterpret_cast<const float4*>(embs + (size_t)a * EDIM)[tid];
        ea[tid * 4 + 0] = v.x;
        ea[tid * 4 + 1] = v.y;
        ea[tid * 4 + 2] = v.z;
        ea[tid * 4 + 3] = v.w;
    }
    // Load labels (512 ints, 2 per thread, coalesced)
    lab[tid]       = labels[tid];
    lab[tid + 256] = labels[tid + 256];
    __syncthreads();

    const int la = lab[a];

    // Distance row: each thread computes d[j] for j = tid, tid+256
    for (int j = tid; j < BSZ; j += 256) {
        const float4* er = reinterpret_cast<const float4*>(embs + (size_t)j * EDIM);
        float acc = 0.f;
#pragma unroll
        for (int k = 0; k < EDIM / 4; ++k) {
            float4 v = er[k];
            acc += sq(ea[4 * k + 0] - v.x);
            acc += sq(ea[4 * k + 1] - v.y);
            acc += sq(ea[4 * k + 2] - v.z);
            acc += sq(ea[4 * k + 3] - v.w);
        }
        d[j] = acc;  // squared L2, >= 0 by construction
    }

    // Deterministic positive-list build (single thread; ~512 cheap iters)
    if (tid == 0) {
        int c = 0;
        for (int j = 0; j < BSZ; ++j)
            if (lab[j] == la && j != a) plist[c++] = j;
        pcnt = c;
    }
    __syncthreads();

    const int np = pcnt;
    float s = 0.f, c = 0.f;
    // Each thread owns negatives n = tid, tid+256
    for (int n = tid; n < BSZ; n += 256) {
        if (lab[n] != la) {
            const float dn = d[n];
            for (int i = 0; i < np; ++i) {
                float l = d[plist[i]] - dn + 1.0f;  // MARGIN = 1.0
                float t = fmaxf(l, 0.f);
                s += t;
                if (t > 1e-16f) c += 1.f;
            }
        }
    }

    // Block reduction: wave shuffle (64-lane) then LDS across 4 waves
#pragma unroll
    for (int off = 32; off; off >>= 1) {
        s += __shfl_down(s, off);
        c += __shfl_down(c, off);
    }
    const int wave = tid >> 6, lane = tid & 63;
    if (lane == 0) { wsum[wave] = s; wcnt[wave] = c; }
    __syncthreads();
    if (tid == 0) {
        sums[a] = wsum[0] + wsum[1] + wsum[2] + wsum[3];
        cnts[a] = wcnt[0] + wcnt[1] + wcnt[2] + wcnt[3];
    }
}

__global__ __launch_bounds__(512) void triplet_finalize(
    const float* __restrict__ sums,
    const float* __restrict__ cnts,
    float* __restrict__ out)
{
    __shared__ float wsum[8], wcnt[8];
    const int tid = threadIdx.x;
    float s = sums[tid];
    float c = cnts[tid];
#pragma unroll
    for (int off = 32; off; off >>= 1) {
        s += __shfl_down(s, off);
        c += __shfl_down(c, off);
    }
    const int wave = tid >> 6, lane = tid & 63;
    if (lane == 0) { wsum[wave] = s; wcnt[wave] = c; }
    __syncthreads();
    if (tid == 0) {
        float S = 0.f, C = 0.f;
#pragma unroll
        for (int w = 0; w < 8; ++w) { S += wsum[w]; C += wcnt[w]; }
        out[0] = S / (C + 1e-16f);
    }
}

extern "C" void kernel_launch(void* const* d_in, const int* in_sizes, int n_in,
                              void* d_out, int out_size, void* d_ws, size_t ws_size,
                              hipStream_t stream)
{
    const float* embs   = reinterpret_cast<const float*>(d_in[0]);
    const int*   labels = reinterpret_cast<const int*>(d_in[1]);
    float*       out    = reinterpret_cast<float*>(d_out);

    float* sums = reinterpret_cast<float*>(d_ws);
    float* cnts = sums + BSZ;

    triplet_rows<<<BSZ, 256, 0, stream>>>(embs, labels, sums, cnts);
    triplet_finalize<<<1, 512, 0, stream>>>(sums, cnts, out);
}

// Round 2
// 32.630 us; speedup vs baseline: 1.5311x; 1.5311x over previous
//
#include <hip/hip_runtime.h>

// BatchAllTripletLoss, B=512, E=128, labels in [0,64), MARGIN=1.0, EPS=1e-16.
// out = sum(hinge) / (count(hinge > EPS) + EPS) over valid (a,p,n).
//
// Plan:
//  K1 dist_tiles: D[i][j] = max(||e_i||^2 + ||e_j||^2 - 2 e_i.e_j, 0)
//     256 blocks (16x16 grid of 32x32 tiles), LDS-staged, coalesced.
//     Block 0 also zeroes the global accumulators (runs before K2 in stream).
//  K2 triplet_pass: one block per anchor; reads dist row (coalesced), builds
//     positive list via ballot-compaction, accumulates hinge sum/count,
//     contributes via fixed-point int64 atomics (deterministic), last block
//     finalizes out[0].

#define BSZ 512
#define EDIM 128
#define TS 32
#define SCALE 1048576.0  // 2^20 fixed-point for the float sum

__global__ __launch_bounds__(256) void dist_tiles(
    const float* __restrict__ embs,
    float* __restrict__ D,
    unsigned long long* __restrict__ accs)  // [0]=sumq [1]=cnt [2]=ctr
{
    __shared__ float At[TS][EDIM + 4];  // stride 132 floats: bank-conflict-friendly
    __shared__ float Bt[TS][EDIM + 4];
    __shared__ float nA[TS], nB[TS];

    const int tid = threadIdx.x;
    const int bi = blockIdx.x >> 4;
    const int bj = blockIdx.x & 15;
    const int I = bi * TS, J = bj * TS;

    if (blockIdx.x == 0 && tid < 3) accs[tid] = 0ull;  // zero accumulators (K2 runs after)

    // Stage 32x128 A-tile and B-tile, coalesced float4 (1024 float4 per tile).
#pragma unroll
    for (int q = 0; q < 4; ++q) {
        int idx = tid + 256 * q;          // 0..1023
        int r   = idx >> 5;               // 32 float4 per row
        int k4  = idx & 31;
        float4 va = reinterpret_cast<const float4*>(embs + (size_t)(I + r) * EDIM)[k4];
        *reinterpret_cast<float4*>(&At[r][k4 * 4]) = va;
        float4 vb = reinterpret_cast<const float4*>(embs + (size_t)(J + r) * EDIM)[k4];
        *reinterpret_cast<float4*>(&Bt[r][k4 * 4]) = vb;
    }
    __syncthreads();

    // Row norms (32 + 32 rows, threads 0..63)
    if (tid < 64) {
        int r = tid & 31;
        float s = 0.f;
        if (tid < 32) {
#pragma unroll
            for (int k = 0; k < EDIM; k += 4) {
                float4 v = *reinterpret_cast<float4*>(&At[r][k]);
                s += v.x * v.x + v.y * v.y + v.z * v.z + v.w * v.w;
            }
            nA[r] = s;
        } else {
#pragma unroll
            for (int k = 0; k < EDIM; k += 4) {
                float4 v = *reinterpret_cast<float4*>(&Bt[r][k]);
                s += v.x * v.x + v.y * v.y + v.z * v.z + v.w * v.w;
            }
            nB[r] = s;
        }
    }
    __syncthreads();

    // 2x2 register blocking: thread (tr,tc) computes rows {tr,tr+16} x cols {tc,tc+16}
    const int tr = tid >> 4, tc = tid & 15;
    float a00 = 0.f, a01 = 0.f, a10 = 0.f, a11 = 0.f;
#pragma unroll 8
    for (int k = 0; k < EDIM; k += 4) {
        float4 x0 = *reinterpret_cast<float4*>(&At[tr][k]);
        float4 x1 = *reinterpret_cast<float4*>(&At[tr + 16][k]);
        float4 y0 = *reinterpret_cast<float4*>(&Bt[tc][k]);
        float4 y1 = *reinterpret_cast<float4*>(&Bt[tc + 16][k]);
        a00 += x0.x * y0.x + x0.y * y0.y + x0.z * y0.z + x0.w * y0.w;
        a01 += x0.x * y1.x + x0.y * y1.y + x0.z * y1.z + x0.w * y1.w;
        a10 += x1.x * y0.x + x1.y * y0.y + x1.z * y0.z + x1.w * y0.w;
        a11 += x1.x * y1.x + x1.y * y1.y + x1.z * y1.z + x1.w * y1.w;
    }
    float* Drow0 = D + (size_t)(I + tr) * BSZ + J;
    float* Drow1 = D + (size_t)(I + tr + 16) * BSZ + J;
    Drow0[tc]      = fmaxf(nA[tr]      + nB[tc]      - 2.f * a00, 0.f);
    Drow0[tc + 16] = fmaxf(nA[tr]      + nB[tc + 16] - 2.f * a01, 0.f);
    Drow1[tc]      = fmaxf(nA[tr + 16] + nB[tc]      - 2.f * a10, 0.f);
    Drow1[tc + 16] = fmaxf(nA[tr + 16] + nB[tc + 16] - 2.f * a11, 0.f);
}

__global__ __launch_bounds__(256) void triplet_pass(
    const float* __restrict__ D,
    const int* __restrict__ labels,
    unsigned long long* __restrict__ accs,  // [0]=sumq [1]=cnt [2]=ctr
    float* __restrict__ out)
{
    __shared__ int   lab[BSZ];
    __shared__ float d[BSZ];
    __shared__ unsigned long long masks[8];
    __shared__ int   plist[128];
    __shared__ float wsum[4];
    __shared__ int   wcnt[4];

    const int a = blockIdx.x, tid = threadIdx.x;
    const int wv = tid >> 6, lane = tid & 63;

    lab[tid]       = labels[tid];
    lab[tid + 256] = labels[tid + 256];
    float2 dv = reinterpret_cast<const float2*>(D + (size_t)a * BSZ)[tid];
    d[tid * 2]     = dv.x;
    d[tid * 2 + 1] = dv.y;
    __syncthreads();

    const int la = lab[a];

    // Ballot-compaction of positives (parallel, deterministic order)
#pragma unroll
    for (int c = 0; c < 2; ++c) {
        int j = c * 256 + tid;
        bool pred = (lab[j] == la) && (j != a);
        unsigned long long m = __ballot(pred);
        if (lane == 0) masks[c * 4 + wv] = m;
    }
    __syncthreads();

    int total = 0;
#pragma unroll
    for (int q = 0; q < 8; ++q) total += __popcll(masks[q]);
    const int np = total < 128 ? total : 128;

#pragma unroll
    for (int c = 0; c < 2; ++c) {
        int j = c * 256 + tid;
        bool pred = (lab[j] == la) && (j != a);
        if (pred) {
            int mi = c * 4 + wv;
            int off = 0;
            for (int q = 0; q < mi; ++q) off += __popcll(masks[q]);
            off += __popcll(masks[mi] & ((1ull << lane) - 1ull));
            if (off < 128) plist[off] = j;
        }
    }
    __syncthreads();

    // Hinge accumulation: each thread owns negatives n = tid, tid+256
    float s = 0.f;
    int   cnt = 0;
#pragma unroll
    for (int c = 0; c < 2; ++c) {
        int n = c * 256 + tid;
        if (lab[n] != la) {
            float dn = d[n];
            for (int i = 0; i < np; ++i) {
                float t = fmaxf(d[plist[i]] - dn + 1.0f, 0.f);
                s += t;
                cnt += (t > 1e-16f) ? 1 : 0;
            }
        }
    }

    // Block reduction
#pragma unroll
    for (int off = 32; off; off >>= 1) {
        s   += __shfl_down(s, off);
        cnt += __shfl_down(cnt, off);
    }
    if (lane == 0) { wsum[wv] = s; wcnt[wv] = cnt; }
    __syncthreads();

    if (tid == 0) {
        float S = wsum[0] + wsum[1] + wsum[2] + wsum[3];
        int   C = wcnt[0] + wcnt[1] + wcnt[2] + wcnt[3];
        unsigned long long q = (unsigned long long)llrint((double)S * SCALE);
        atomicAdd(&accs[0], q);
        atomicAdd(&accs[1], (unsigned long long)C);
        __threadfence();
        unsigned int done = (unsigned int)atomicAdd(&accs[2], 1ull);
        if (done == BSZ - 1) {
            unsigned long long Sq = atomicAdd(&accs[0], 0ull);
            unsigned long long Cq = atomicAdd(&accs[1], 0ull);
            double Sd = (double)Sq / SCALE;
            out[0] = (float)(Sd / ((double)Cq + 1e-16));
        }
    }
}

extern "C" void kernel_launch(void* const* d_in, const int* in_sizes, int n_in,
                              void* d_out, int out_size, void* d_ws, size_t ws_size,
                              hipStream_t stream)
{
    const float* embs   = reinterpret_cast<const float*>(d_in[0]);
    const int*   labels = reinterpret_cast<const int*>(d_in[1]);
    float*       out    = reinterpret_cast<float*>(d_out);

    unsigned long long* accs = reinterpret_cast<unsigned long long*>(d_ws);
    float* D = reinterpret_cast<float*>(reinterpret_cast<char*>(d_ws) + 256);

    dist_tiles<<<256, 256, 0, stream>>>(embs, D, accs);
    triplet_pass<<<BSZ, 256, 0, stream>>>(D, labels, accs, out);
}

// Round 3
// 22.416 us; speedup vs baseline: 2.2288x; 1.4557x over previous
//
#include <hip/hip_runtime.h>

// BatchAllTripletLoss, B=512, E=128, labels in [0,64), MARGIN=1.0, EPS=1e-16.
// out = sum(hinge) / (count(hinge > EPS) + EPS) over valid (a,p,n).
//
// K1 fused_pass: 256 blocks, 2 anchors per block. Dist rows computed with
//    direct coalesced float4 loads (embs is L2-resident; anchor strip lives
//    in registers), 4-thread-group shuffle reduction. Then ballot-compacted
//    positive list + per-thread hinge accumulation. Per-anchor partials to
//    d_ws. No atomics, fully deterministic.
// K2 finalize: one block reduces 512 partials, writes out.

#define BSZ 512
#define EDIM 128
#define NPOSMAX 96

__global__ __launch_bounds__(256) void fused_pass(
    const float* __restrict__ embs,
    const int* __restrict__ labels,
    float* __restrict__ sums,
    float* __restrict__ cnts)
{
    __shared__ float d0[BSZ], d1[BSZ];
    __shared__ int   lab[BSZ];
    __shared__ unsigned long long masks0[8], masks1[8];
    __shared__ int   plist0[NPOSMAX], plist1[NPOSMAX];
    __shared__ float wsum0[4], wsum1[4];
    __shared__ int   wcnt0[4], wcnt1[4];

    const int tid  = threadIdx.x;
    const int a0   = blockIdx.x * 2, a1 = a0 + 1;
    const int q    = tid & 3;        // k-quarter: floats [q*32, q*32+32)
    const int r0   = tid >> 2;       // row group 0..63
    const int wv   = tid >> 6, lane = tid & 63;

    lab[tid]       = labels[tid];
    lab[tid + 256] = labels[tid + 256];

    // Anchor k-strips in registers (reused across all 8 row passes)
    float4 ea0[8], ea1[8];
    const float4* A0 = reinterpret_cast<const float4*>(embs + (size_t)a0 * EDIM) + q * 8;
    const float4* A1 = reinterpret_cast<const float4*>(embs + (size_t)a1 * EDIM) + q * 8;
#pragma unroll
    for (int i = 0; i < 8; ++i) { ea0[i] = A0[i]; ea1[i] = A1[i]; }

    // Distance rows: 4 threads per row, 32 dims each, shuffle-combine.
#pragma unroll 2
    for (int t = 0; t < 8; ++t) {
        const int r = r0 + 64 * t;
        const float4* row = reinterpret_cast<const float4*>(embs + (size_t)r * EDIM) + q * 8;
        float acc0 = 0.f, acc1 = 0.f;
#pragma unroll
        for (int i = 0; i < 8; ++i) {
            float4 x = row[i];
            float u;
            u = x.x - ea0[i].x; acc0 = fmaf(u, u, acc0);
            u = x.y - ea0[i].y; acc0 = fmaf(u, u, acc0);
            u = x.z - ea0[i].z; acc0 = fmaf(u, u, acc0);
            u = x.w - ea0[i].w; acc0 = fmaf(u, u, acc0);
            u = x.x - ea1[i].x; acc1 = fmaf(u, u, acc1);
            u = x.y - ea1[i].y; acc1 = fmaf(u, u, acc1);
            u = x.z - ea1[i].z; acc1 = fmaf(u, u, acc1);
            u = x.w - ea1[i].w; acc1 = fmaf(u, u, acc1);
        }
        acc0 += __shfl_xor(acc0, 1); acc0 += __shfl_xor(acc0, 2);
        acc1 += __shfl_xor(acc1, 1); acc1 += __shfl_xor(acc1, 2);
        if (q == 0) { d0[r] = acc0; d1[r] = acc1; }
    }
    __syncthreads();

    const int la0 = lab[a0], la1 = lab[a1];

    // Ballot-compaction of positives (parallel, deterministic)
#pragma unroll
    for (int c = 0; c < 2; ++c) {
        int j = c * 256 + tid;
        unsigned long long m0 = __ballot(lab[j] == la0 && j != a0);
        unsigned long long m1 = __ballot(lab[j] == la1 && j != a1);
        if (lane == 0) { masks0[c * 4 + wv] = m0; masks1[c * 4 + wv] = m1; }
    }
    __syncthreads();

    int np0 = 0, np1 = 0;
#pragma unroll
    for (int m = 0; m < 8; ++m) { np0 += __popcll(masks0[m]); np1 += __popcll(masks1[m]); }
    if (np0 > NPOSMAX) np0 = NPOSMAX;
    if (np1 > NPOSMAX) np1 = NPOSMAX;

#pragma unroll
    for (int c = 0; c < 2; ++c) {
        int j = c * 256 + tid;
        if (lab[j] == la0 && j != a0) {
            int mi = c * 4 + wv, off = 0;
            for (int m = 0; m < mi; ++m) off += __popcll(masks0[m]);
            off += __popcll(masks0[mi] & ((1ull << lane) - 1ull));
            if (off < NPOSMAX) plist0[off] = j;
        }
        if (lab[j] == la1 && j != a1) {
            int mi = c * 4 + wv, off = 0;
            for (int m = 0; m < mi; ++m) off += __popcll(masks1[m]);
            off += __popcll(masks1[mi] & ((1ull << lane) - 1ull));
            if (off < NPOSMAX) plist1[off] = j;
        }
    }
    __syncthreads();

    // Hinge accumulation
    float s0 = 0.f, s1 = 0.f;
    int   c0 = 0,   c1 = 0;
#pragma unroll
    for (int h = 0; h < 2; ++h) {
        int n = h * 256 + tid;
        int ln = lab[n];
        if (ln != la0) {
            float dn = d0[n];
            for (int i = 0; i < np0; ++i) {
                float t = fmaxf(d0[plist0[i]] - dn + 1.0f, 0.f);
                s0 += t; c0 += (t > 1e-16f) ? 1 : 0;
            }
        }
        if (ln != la1) {
            float dn = d1[n];
            for (int i = 0; i < np1; ++i) {
                float t = fmaxf(d1[plist1[i]] - dn + 1.0f, 0.f);
                s1 += t; c1 += (t > 1e-16f) ? 1 : 0;
            }
        }
    }

    // Block reduction (deterministic tree)
#pragma unroll
    for (int off = 32; off; off >>= 1) {
        s0 += __shfl_down(s0, off); c0 += __shfl_down(c0, off);
        s1 += __shfl_down(s1, off); c1 += __shfl_down(c1, off);
    }
    if (lane == 0) { wsum0[wv] = s0; wcnt0[wv] = c0; wsum1[wv] = s1; wcnt1[wv] = c1; }
    __syncthreads();
    if (tid == 0) {
        sums[a0] = wsum0[0] + wsum0[1] + wsum0[2] + wsum0[3];
        cnts[a0] = (float)(wcnt0[0] + wcnt0[1] + wcnt0[2] + wcnt0[3]);
        sums[a1] = wsum1[0] + wsum1[1] + wsum1[2] + wsum1[3];
        cnts[a1] = (float)(wcnt1[0] + wcnt1[1] + wcnt1[2] + wcnt1[3]);
    }
}

__global__ __launch_bounds__(512) void finalize(
    const float* __restrict__ sums,
    const float* __restrict__ cnts,
    float* __restrict__ out)
{
    __shared__ float wsum[8], wcnt[8];
    const int tid = threadIdx.x;
    float s = sums[tid];
    float c = cnts[tid];
#pragma unroll
    for (int off = 32; off; off >>= 1) {
        s += __shfl_down(s, off);
        c += __shfl_down(c, off);
    }
    const int wv = tid >> 6, lane = tid & 63;
    if (lane == 0) { wsum[wv] = s; wcnt[wv] = c; }
    __syncthreads();
    if (tid == 0) {
        float S = 0.f, C = 0.f;
#pragma unroll
        for (int w = 0; w < 8; ++w) { S += wsum[w]; C += wcnt[w]; }
        out[0] = S / (C + 1e-16f);
    }
}

extern "C" void kernel_launch(void* const* d_in, const int* in_sizes, int n_in,
                              void* d_out, int out_size, void* d_ws, size_t ws_size,
                              hipStream_t stream)
{
    const float* embs   = reinterpret_cast<const float*>(d_in[0]);
    const int*   labels = reinterpret_cast<const int*>(d_in[1]);
    float*       out    = reinterpret_cast<float*>(d_out);

    float* sums = reinterpret_cast<float*>(d_ws);
    float* cnts = sums + BSZ;

    fused_pass<<<BSZ / 2, 256, 0, stream>>>(embs, labels, sums, cnts);
    finalize<<<1, 512, 0, stream>>>(sums, cnts, out);
}

// Round 4
// 16.324 us; speedup vs baseline: 3.0605x; 1.3732x over previous
//
#include <hip/hip_runtime.h>

// BatchAllTripletLoss, B=512, E=128, labels in [0,64), MARGIN=1.0, EPS=1e-16.
// out = sum(hinge) / (count(hinge > EPS) + EPS) over valid (a,p,n).
//
// K1 dist_tiles:  D[i][j] = max(n_i + n_j - 2 e_i.e_j, 0), 16x16 grid of
//                 32x32 tiles, LDS-staged coalesced float4, 2x2 reg blocking.
// K2 triplet_pass: one block per anchor, reads D row coalesced (L2-hit),
//                 ballot-compacted positive list, hinge accum, per-anchor
//                 partials to d_ws. No atomics -> deterministic.
// K3 finalize:    one block reduces 512 partials, writes out[0].

#define BSZ 512
#define EDIM 128
#define TS 32
#define NPOSMAX 96

__global__ __launch_bounds__(256) void dist_tiles(
    const float* __restrict__ embs,
    float* __restrict__ D)
{
    __shared__ float At[TS][EDIM + 4];
    __shared__ float Bt[TS][EDIM + 4];
    __shared__ float nA[TS], nB[TS];

    const int tid = threadIdx.x;
    const int bi = blockIdx.x >> 4;
    const int bj = blockIdx.x & 15;
    const int I = bi * TS, J = bj * TS;

    // Stage 32x128 A-tile and B-tile, coalesced float4.
#pragma unroll
    for (int q = 0; q < 4; ++q) {
        int idx = tid + 256 * q;          // 0..1023
        int r   = idx >> 5;
        int k4  = idx & 31;
        float4 va = reinterpret_cast<const float4*>(embs + (size_t)(I + r) * EDIM)[k4];
        *reinterpret_cast<float4*>(&At[r][k4 * 4]) = va;
        float4 vb = reinterpret_cast<const float4*>(embs + (size_t)(J + r) * EDIM)[k4];
        *reinterpret_cast<float4*>(&Bt[r][k4 * 4]) = vb;
    }
    __syncthreads();

    if (tid < 64) {
        int r = tid & 31;
        float s = 0.f;
        if (tid < 32) {
#pragma unroll
            for (int k = 0; k < EDIM; k += 4) {
                float4 v = *reinterpret_cast<float4*>(&At[r][k]);
                s += v.x * v.x + v.y * v.y + v.z * v.z + v.w * v.w;
            }
            nA[r] = s;
        } else {
#pragma unroll
            for (int k = 0; k < EDIM; k += 4) {
                float4 v = *reinterpret_cast<float4*>(&Bt[r][k]);
                s += v.x * v.x + v.y * v.y + v.z * v.z + v.w * v.w;
            }
            nB[r] = s;
        }
    }
    __syncthreads();

    const int tr = tid >> 4, tc = tid & 15;
    float a00 = 0.f, a01 = 0.f, a10 = 0.f, a11 = 0.f;
#pragma unroll 8
    for (int k = 0; k < EDIM; k += 4) {
        float4 x0 = *reinterpret_cast<float4*>(&At[tr][k]);
        float4 x1 = *reinterpret_cast<float4*>(&At[tr + 16][k]);
        float4 y0 = *reinterpret_cast<float4*>(&Bt[tc][k]);
        float4 y1 = *reinterpret_cast<float4*>(&Bt[tc + 16][k]);
        a00 += x0.x * y0.x + x0.y * y0.y + x0.z * y0.z + x0.w * y0.w;
        a01 += x0.x * y1.x + x0.y * y1.y + x0.z * y1.z + x0.w * y1.w;
        a10 += x1.x * y0.x + x1.y * y0.y + x1.z * y0.z + x1.w * y0.w;
        a11 += x1.x * y1.x + x1.y * y1.y + x1.z * y1.z + x1.w * y1.w;
    }
    float* Drow0 = D + (size_t)(I + tr) * BSZ + J;
    float* Drow1 = D + (size_t)(I + tr + 16) * BSZ + J;
    Drow0[tc]      = fmaxf(nA[tr]      + nB[tc]      - 2.f * a00, 0.f);
    Drow0[tc + 16] = fmaxf(nA[tr]      + nB[tc + 16] - 2.f * a01, 0.f);
    Drow1[tc]      = fmaxf(nA[tr + 16] + nB[tc]      - 2.f * a10, 0.f);
    Drow1[tc + 16] = fmaxf(nA[tr + 16] + nB[tc + 16] - 2.f * a11, 0.f);
}

__global__ __launch_bounds__(256) void triplet_pass(
    const float* __restrict__ D,
    const int* __restrict__ labels,
    float* __restrict__ sums,
    float* __restrict__ cnts)
{
    __shared__ int   lab[BSZ];
    __shared__ float d[BSZ];
    __shared__ unsigned long long masks[8];
    __shared__ int   plist[NPOSMAX];
    __shared__ float wsum[4];
    __shared__ int   wcnt[4];

    const int a = blockIdx.x, tid = threadIdx.x;
    const int wv = tid >> 6, lane = tid & 63;

    lab[tid]       = labels[tid];
    lab[tid + 256] = labels[tid + 256];
    float2 dv = reinterpret_cast<const float2*>(D + (size_t)a * BSZ)[tid];
    d[tid * 2]     = dv.x;
    d[tid * 2 + 1] = dv.y;
    __syncthreads();

    const int la = lab[a];

#pragma unroll
    for (int c = 0; c < 2; ++c) {
        int j = c * 256 + tid;
        unsigned long long m = __ballot(lab[j] == la && j != a);
        if (lane == 0) masks[c * 4 + wv] = m;
    }
    __syncthreads();

    int np = 0;
#pragma unroll
    for (int m = 0; m < 8; ++m) np += __popcll(masks[m]);
    if (np > NPOSMAX) np = NPOSMAX;

#pragma unroll
    for (int c = 0; c < 2; ++c) {
        int j = c * 256 + tid;
        if (lab[j] == la && j != a) {
            int mi = c * 4 + wv, off = 0;
            for (int m = 0; m < mi; ++m) off += __popcll(masks[m]);
            off += __popcll(masks[mi] & ((1ull << lane) - 1ull));
            if (off < NPOSMAX) plist[off] = j;
        }
    }
    __syncthreads();

    float s = 0.f;
    int   cnt = 0;
#pragma unroll
    for (int c = 0; c < 2; ++c) {
        int n = c * 256 + tid;
        if (lab[n] != la) {
            float dn = d[n];
            for (int i = 0; i < np; ++i) {
                float t = fmaxf(d[plist[i]] - dn + 1.0f, 0.f);
                s += t;
                cnt += (t > 1e-16f) ? 1 : 0;
            }
        }
    }

#pragma unroll
    for (int off = 32; off; off >>= 1) {
        s   += __shfl_down(s, off);
        cnt += __shfl_down(cnt, off);
    }
    if (lane == 0) { wsum[wv] = s; wcnt[wv] = cnt; }
    __syncthreads();
    if (tid == 0) {
        sums[a] = wsum[0] + wsum[1] + wsum[2] + wsum[3];
        cnts[a] = (float)(wcnt[0] + wcnt[1] + wcnt[2] + wcnt[3]);
    }
}

__global__ __launch_bounds__(512) void finalize(
    const float* __restrict__ sums,
    const float* __restrict__ cnts,
    float* __restrict__ out)
{
    __shared__ float wsum[8], wcnt[8];
    const int tid = threadIdx.x;
    float s = sums[tid];
    float c = cnts[tid];
#pragma unroll
    for (int off = 32; off; off >>= 1) {
        s += __shfl_down(s, off);
        c += __shfl_down(c, off);
    }
    const int wv = tid >> 6, lane = tid & 63;
    if (lane == 0) { wsum[wv] = s; wcnt[wv] = c; }
    __syncthreads();
    if (tid == 0) {
        float S = 0.f, C = 0.f;
#pragma unroll
        for (int w = 0; w < 8; ++w) { S += wsum[w]; C += wcnt[w]; }
        out[0] = S / (C + 1e-16f);
    }
}

extern "C" void kernel_launch(void* const* d_in, const int* in_sizes, int n_in,
                              void* d_out, int out_size, void* d_ws, size_t ws_size,
                              hipStream_t stream)
{
    const float* embs   = reinterpret_cast<const float*>(d_in[0]);
    const int*   labels = reinterpret_cast<const int*>(d_in[1]);
    float*       out    = reinterpret_cast<float*>(d_out);

    float* D    = reinterpret_cast<float*>(d_ws);                 // 1 MB
    float* sums = D + (size_t)BSZ * BSZ;                          // 2 KB
    float* cnts = sums + BSZ;                                     // 2 KB

    dist_tiles<<<256, 256, 0, stream>>>(embs, D);
    triplet_pass<<<BSZ, 256, 0, stream>>>(D, labels, sums, cnts);
    finalize<<<1, 512, 0, stream>>>(sums, cnts, out);
}